// Round 11
// baseline (158.987 us; speedup 1.0000x reference)
//
#include <hip/hip_runtime.h>
#include <stdint.h>

typedef unsigned int u32;
typedef int v4i  __attribute__((ext_vector_type(4)));
typedef int v16i __attribute__((ext_vector_type(16)));

#define K_MSG   1024
#define N_CODE  2048
#define NB      32768

// ---------------- pack b -> i8: [NB][1024] int32 -> [NB][1024] i8 -----------
__global__ void pack_bi8(const int* __restrict__ b, u32* __restrict__ bi8) {
    const int nthr = gridDim.x * blockDim.x;
    int idx = blockIdx.x * blockDim.x + threadIdx.x;
    const int ndw = NB * K_MSG / 4;                 // output dwords
    for (; idx < ndw; idx += nthr) {
        int4 v = *(const int4*)(b + (size_t)idx * 4);
        bi8[idx] = (u32)(v.x & 1) | ((u32)(v.y & 1) << 8) |
                   ((u32)(v.z & 1) << 16) | ((u32)(v.w & 1) << 24);
    }
}

// ------------- pack G -> fragment-major i8 B (proven in round 10) -----------
// BF tile = one MFMA B-fragment (32 cols x 32 k) = 1024 B in LANE order:
// a wave's frag load is base + lane*16 -> one fully-coalesced dwordx4.
__global__ void pack_gBF(const int* __restrict__ G, u32* __restrict__ bf) {
    int idx = blockIdx.x * blockDim.x + threadIdx.x;   // 524288
    const int j  = idx & (N_CODE - 1);                 // coalesced G reads
    const int kq = idx >> 11;                          // dword of k: 0..255
    u32 p = 0;
#pragma unroll
    for (int i = 0; i < 4; ++i) {
        int v = G[(size_t)(kq * 4 + i) * N_CODE + j];
        p |= (u32)(v & 1) << (8 * i);
    }
    const int jb = j >> 5, jr = j & 31;
    const int kb = kq >> 3, hi = (kq >> 2) & 1, b4 = kq & 3;
    bf[(size_t)(jb * 32 + kb) * 256 + hi * 128 + jr * 4 + b4] = p;
}

// ---------------- MFMA GEMM, wave tile 128x64 (B-L2-rate halved) ------------
// Block 256 thr = 4 waves, block tile 128 rows x 256 cols. A staged in LDS one
// K-half at a time (64 KB -> 2 blocks/CU). Per k-step/wave: 4 ds_read_b128 (A)
// + 2 coalesced 1KB B-frag loads (L2) + 8 MFMA. acc 4x2 v16i = 128 VGPR.

#define MFMA_I8(va, vb, vc) __builtin_amdgcn_mfma_i32_32x32x32_i8(va, vb, vc, 0, 0, 0)

#define MFMA_SET(sfx) do {                       \
    acc[0][0] = MFMA_I8(a0, b0##sfx, acc[0][0]); \
    acc[0][1] = MFMA_I8(a0, b1##sfx, acc[0][1]); \
    acc[1][0] = MFMA_I8(a1, b0##sfx, acc[1][0]); \
    acc[1][1] = MFMA_I8(a1, b1##sfx, acc[1][1]); \
    acc[2][0] = MFMA_I8(a2, b0##sfx, acc[2][0]); \
    acc[2][1] = MFMA_I8(a2, b1##sfx, acc[2][1]); \
    acc[3][0] = MFMA_I8(a3, b0##sfx, acc[3][0]); \
    acc[3][1] = MFMA_I8(a3, b1##sfx, acc[3][1]); \
} while (0)

// swizzle uses lr&7 only (rows mi*32+lr share it), so one offset for all 4 frags
#define LDA(s_)                                                \
    const int ao_ = (((s_) * 32) + hi * 16) ^ axor;            \
    v4i a0 = *(const v4i*)(As + (lr      ) * 512 + ao_);       \
    v4i a1 = *(const v4i*)(As + (lr +  32) * 512 + ao_);       \
    v4i a2 = *(const v4i*)(As + (lr +  64) * 512 + ao_);       \
    v4i a3 = *(const v4i*)(As + (lr +  96) * 512 + ao_);

#define LOADB(sfx, s_) do {                                    \
    b0##sfx = *(const v4i*)(bp0 + (size_t)(s_) * 1024);        \
    b1##sfx = *(const v4i*)(bp1 + (size_t)(s_) * 1024);        \
} while (0)

__global__ __launch_bounds__(256, 2) void gemm_i8(const char* __restrict__ bi8,
                                                  const char* __restrict__ bf,
                                                  int* __restrict__ out) {
    __shared__ __align__(16) char As[128 * 512];    // 64 KB: 128 rows x 512B K-half

    const int t   = threadIdx.x;
    // bijective XCD swizzle (2048 % 8 == 0): XCD k owns disjoint M-panels.
    const int bid = blockIdx.x;
    const int swz = (bid & 7) * 256 + (bid >> 3);
    const int m0  = (swz >> 3) * 128;
    const int n0  = (swz & 7) * 256;

    const int w = t >> 6, lane = t & 63, lr = lane & 31, hi = lane >> 5;
    const int strow = t >> 1, sc = t & 1;           // staging: row, 256B-half
    const int axor  = (lr & 7) << 4;

    // fragment-major B bases: colblk = n0/32 + w*2 + ni, frag stride 32KB
    const char* bp0 = bf + ((size_t)(n0 >> 5) + w * 2) * 32768 + lane * 16;
    const char* bp1 = bp0 + 32768;

    const char* asrc = bi8 + (size_t)(m0 + strow) * 1024 + sc * 256;
    char* adst = As + strow * 512;
    const int dxor = (strow & 7) << 4;

    v16i acc[4][2] = {};
    v4i b0A, b1A, b0B, b1B;

#pragma unroll 1
    for (int ph = 0; ph < 2; ++ph) {
        if (ph) __syncthreads();                    // all reads of prev half done
        // stage K-half: 128 rows x 512B, each thread 256B contiguous, swizzled
#pragma unroll
        for (int i = 0; i < 16; ++i) {
            uint4 v = *(const uint4*)(asrc + ph * 512 + i * 16);
            *(uint4*)(adst + ((sc * 256 + i * 16) ^ dxor)) = v;
        }
        __syncthreads();

        const int kb = ph * 16;
        LOADB(A, kb + 0);
        LOADB(B, kb + 1);
#pragma unroll 1
        for (int sl = 0; sl < 16; sl += 2) {
            {
                LDA(sl)
                MFMA_SET(A);
                if (sl + 2 < 16) LOADB(A, kb + sl + 2);
            }
            {
                LDA(sl + 1)
                MFMA_SET(B);
                if (sl + 3 < 16) LOADB(B, kb + sl + 3);
            }
        }
    }

    // epilogue: parity = acc & 1 (C/D: col=lane&31, row=(r&3)+8*(r>>2)+4*hi)
#pragma unroll
    for (int mi = 0; mi < 4; ++mi) {
#pragma unroll
        for (int ni = 0; ni < 2; ++ni) {
            const int cbase = n0 + w * 64 + ni * 32 + lr;
            const int rbase = m0 + mi * 32 + 4 * hi;
#pragma unroll
            for (int r = 0; r < 16; ++r) {
                const int row = rbase + (r & 3) + 8 * (r >> 2);
                out[(size_t)row * N_CODE + cbase] = acc[mi][ni][r] & 1;
            }
        }
    }
}

// ---------------- fallback (only if ws too small) ---------------------------
__global__ void encode_naive(const int* __restrict__ b, const int* __restrict__ G,
                             int* __restrict__ out) {
    size_t idx = (size_t)blockIdx.x * blockDim.x + threadIdx.x;
    size_t total = (size_t)NB * N_CODE;
    if (idx >= total) return;
    int i = (int)(idx / N_CODE);
    int j = (int)(idx % N_CODE);
    int acc = 0;
    for (int k = 0; k < K_MSG; ++k)
        acc ^= b[(size_t)i * K_MSG + k] & G[(size_t)k * N_CODE + j];
    out[idx] = acc & 1;
}

extern "C" void kernel_launch(void* const* d_in, const int* in_sizes, int n_in,
                              void* d_out, int out_size, void* d_ws, size_t ws_size,
                              hipStream_t stream) {
    const int* b = (const int*)d_in[0];
    const int* G = (const int*)d_in[1];
    int* out = (int*)d_out;

    const size_t bi8_bytes = (size_t)NB * K_MSG;          // 32 MiB
    const size_t bf_bytes  = (size_t)N_CODE * K_MSG;      // 2 MiB

    if (ws_size < bi8_bytes + bf_bytes) {
        size_t total = (size_t)NB * N_CODE;
        encode_naive<<<(unsigned)((total + 255) / 256), 256, 0, stream>>>(b, G, out);
        return;
    }

    char* bi8 = (char*)d_ws;
    char* bf  = (char*)d_ws + bi8_bytes;

    pack_bi8<<<2048, 256, 0, stream>>>(b, (u32*)bi8);
    pack_gBF<<<2048, 256, 0, stream>>>(G, (u32*)bf);

    gemm_i8<<<2048, 256, 0, stream>>>(bi8, bf, out);   // (NB/128)*(N_CODE/256)
}